// Round 5
// baseline (1324.006 us; speedup 1.0000x reference)
//
#include <hip/hip_runtime.h>
#include <math.h>

typedef __attribute__((ext_vector_type(4))) float f32x4;
typedef __attribute__((ext_vector_type(8))) short bf16x8;

#define DI __device__ __forceinline__

DI unsigned short f32_to_bf16(float f) {
  unsigned int u = __float_as_uint(f);
  u += 0x7FFFu + ((u >> 16) & 1u);   // round-to-nearest-even
  return (unsigned short)(u >> 16);
}

static constexpr float kCode[16] = {
    -1.0f, -0.6961928009986877f, -0.5250730514526367f, -0.39491748809814453f,
    -0.28444138169288635f, -0.18477343022823334f, -0.09105003625154495f, 0.0f,
    0.07958029955625534f, 0.16093020141124725f, 0.24611230194568634f,
    0.33791524171829224f, 0.44070982933044434f, 0.5626170039176941f,
    0.7229568362236023f, 1.0f};

// ---------------------------------------------------------------------------
// NF4 quant-dequant (block=64): 16 lanes/block, float4/lane.
// ---------------------------------------------------------------------------
__global__ void __launch_bounds__(256) k_dequant_nf4(
    const float* __restrict__ in, unsigned short* __restrict__ out, int n4) {
  int i = blockIdx.x * 256 + threadIdx.x;
  if (i >= n4) return;
  f32x4 v = reinterpret_cast<const f32x4*>(in)[i];
  float am = fmaxf(fmaxf(fabsf(v.x), fabsf(v.y)), fmaxf(fabsf(v.z), fabsf(v.w)));
  am = fmaxf(am, __shfl_xor(am, 1));
  am = fmaxf(am, __shfl_xor(am, 2));
  am = fmaxf(am, __shfl_xor(am, 4));
  am = fmaxf(am, __shfl_xor(am, 8));
  float scale = (am == 0.0f) ? 1.0f : am;
  unsigned short o[4];
#pragma unroll
  for (int j = 0; j < 4; ++j) {
    float nv = ((const float*)&v)[j] / scale;
    int idx = 0;
#pragma unroll
    for (int b = 0; b < 15; ++b)
      idx += (nv > 0.5f * (kCode[b] + kCode[b + 1])) ? 1 : 0;
    o[j] = f32_to_bf16(kCode[idx] * am);
  }
  reinterpret_cast<ushort4*>(out)[i] = make_ushort4(o[0], o[1], o[2], o[3]);
}

__global__ void __launch_bounds__(256) k_f32_to_bf16(
    const float* __restrict__ in, unsigned short* __restrict__ out, int n4) {
  int i = blockIdx.x * 256 + threadIdx.x;
  if (i >= n4) return;
  f32x4 v = reinterpret_cast<const f32x4*>(in)[i];
  reinterpret_cast<ushort4*>(out)[i] =
      make_ushort4(f32_to_bf16(v.x), f32_to_bf16(v.y), f32_to_bf16(v.z), f32_to_bf16(v.w));
}

// ---------------------------------------------------------------------------
// GEMM helpers. BK=32, LDS rows = 64B. Element (r,k): byte =
//   r*64 + (((k>>3) ^ ((r>>1)&3))<<4) + (k&7)*2   (round-4 verified swizzle)
// Stage (linear LDS write): lane l of a 1KB unit covers row 16u+(l>>2),
//   global k-chunk (l&3)^((l>>3)&3).
// Read: byte = (rowbase+(l&15))*64 + (((l>>4) ^ ((l>>1)&3))<<4) -> conflict-free.
// ---------------------------------------------------------------------------
DI void gload16(const void* g, void* l) {
  __builtin_amdgcn_global_load_lds(
      (const __attribute__((address_space(1))) void*)g,
      (__attribute__((address_space(3))) void*)l, 16, 0, 0);
}

DI void barrier_nodrain() {
  asm volatile("" ::: "memory");
  __builtin_amdgcn_s_barrier();
  asm volatile("" ::: "memory");
}

#define WAITV(N) asm volatile("s_waitcnt vmcnt(" #N ")" ::: "memory")

// ---------------------------------------------------------------------------
// Fused dual GEMM + SwiGLU. BM=256, B-panel = [W1(128); W2(128)] rows, BK=32.
// 8 waves (2M x 4N), per-wave 128x64. Phase-locked m201-style schedule:
// 2 phases/tile (m-half), 16 MFMA/phase, 2 stage-gloads/phase into buf
// (t+2)&3, counted WAITV(4) once/tile. 4 bufs x 32KB = 128 KiB.
// A strip-halves: h=0 -> block rows [0,64)+[128,192); h=1 -> [64,128)+[192,256)
// so each wave's m-frags 0-3 live in h=0, 4-7 in h=1.
// Epilogue: gate/up wave-pair exchange via LDS (dead staging space).
// ---------------------------------------------------------------------------
__global__ void __launch_bounds__(512, 2) k_gemm_dual_swiglu(
    const unsigned short* __restrict__ X,
    const unsigned short* __restrict__ W1,
    const unsigned short* __restrict__ W2,
    unsigned short* __restrict__ H) {
  constexpr int K = 4096, N = 11008, NK = K / 32;
  __shared__ char ldsb[131072];

  const int tid = threadIdx.x;
  const int w = tid >> 6, l = tid & 63;

  const int bid = blockIdx.x;               // 1376 = 8 * 172
  const int lt = (bid & 7) * 172 + (bid >> 3);
  const int mt = lt & 15, nt = lt >> 4;
  const int m0 = mt * 256, n0 = nt * 128;

  const int wr = w >> 2, wc = w & 3;

  // staging sources (pre-inverse-swizzled). Wave w stages region rows 16w..16w+15.
  const int lrow = l >> 2;                              // 0..15
  const int kc8 = (((l & 3) ^ ((l >> 3) & 3)) << 3);    // elem col 0,8,16,24
  const int arow = (w & 3) * 16 + (w >> 2) * 128;       // strip mapping
  const unsigned short* sA[2] = {
      X + (size_t)(m0 + arow + lrow) * K + kc8,
      X + (size_t)(m0 + 64 + arow + lrow) * K + kc8};
  const unsigned short* sB[2] = {
      W1 + (size_t)(n0 + 16 * w + lrow) * K + kc8,
      W2 + (size_t)(n0 + 16 * w + lrow) * K + kc8};

#define STG(t, h) { const int bo_ = ((t) & 3) * 32768 + (h) * 8192 + w * 1024; \
    gload16(sA[h] + (size_t)(t) * 32, ldsb + bo_);                              \
    gload16(sB[h] + (size_t)(t) * 32, ldsb + bo_ + 16384); }

  // read bases
  const int roff = (((l >> 4) ^ ((l >> 1) & 3)) << 4);
  const char* rdA = ldsb + (wr * 64 + (l & 15)) * 64 + roff;          // +h*8192+m*1024
  const char* rdB = ldsb + 16384 + (wc * 64 + (l & 15)) * 64 + roff;  // +n*1024

  f32x4 acc[8][4] = {};
  bf16x8 a[4], b[4];

  // prologue: tiles 0,1 fully staged (8 loads)
  STG(0, 0); STG(0, 1); STG(1, 0); STG(1, 1);
  WAITV(4);
  barrier_nodrain();

  for (int t = 0; t < NK; ++t) {
    const int bo = (t & 3) * 32768;
    // ---- phase 1: m-half 0 ----
#pragma unroll
    for (int m = 0; m < 4; ++m) a[m] = *(const bf16x8*)(rdA + bo + m * 1024);
#pragma unroll
    for (int n = 0; n < 4; ++n) b[n] = *(const bf16x8*)(rdB + bo + n * 1024);
    if (t + 2 < NK) STG(t + 2, 0);
    barrier_nodrain();
    __builtin_amdgcn_s_setprio(1);
#pragma unroll
    for (int m = 0; m < 4; ++m)
#pragma unroll
      for (int n = 0; n < 4; ++n)
        acc[m][n] = __builtin_amdgcn_mfma_f32_16x16x32_bf16(a[m], b[n], acc[m][n], 0, 0, 0);
    __builtin_amdgcn_s_setprio(0);
    barrier_nodrain();
    // ---- phase 2: m-half 1 ----
#pragma unroll
    for (int m = 0; m < 4; ++m) a[m] = *(const bf16x8*)(rdA + bo + 8192 + m * 1024);
    if (t + 2 < NK) STG(t + 2, 1);
    barrier_nodrain();
    __builtin_amdgcn_s_setprio(1);
#pragma unroll
    for (int m = 0; m < 4; ++m)
#pragma unroll
      for (int n = 0; n < 4; ++n)
        acc[m + 4][n] = __builtin_amdgcn_mfma_f32_16x16x32_bf16(a[m], b[n], acc[m + 4][n], 0, 0, 0);
    __builtin_amdgcn_s_setprio(0);
    if (t + 2 < NK)      { WAITV(4); }
    else if (t + 1 < NK) { WAITV(0); }
    barrier_nodrain();
  }
#undef STG

  // ---- epilogue: gate/up pairwise exchange (m-split), SwiGLU, store ----
  // wave (wr,wc<2) = gate for cols n0+wc*64..; partner w^2 = up, same cols.
  const bool isGate = (wc < 2);
  char* myreg = ldsb + w * 16384;
  const char* pareg = ldsb + (w ^ 2) * 16384;
#pragma unroll
  for (int m2 = 0; m2 < 2; ++m2)    // split writes around barrier-free region
#pragma unroll
    for (int n = 0; n < 4; ++n) {
      const int ms = isGate ? (m2 + 4) : m2;
      *(f32x4*)(myreg + ((m2 * 4 + n) * 64 + l) * 16) = acc[ms][n];
    }
#pragma unroll
  for (int m2 = 2; m2 < 4; ++m2)
#pragma unroll
    for (int n = 0; n < 4; ++n) {
      const int ms = isGate ? (m2 + 4) : m2;
      *(f32x4*)(myreg + ((m2 * 4 + n) * 64 + l) * 16) = acc[ms][n];
    }
  barrier_nodrain();
  const int er = (l >> 4) * 4, ec = l & 15;
#pragma unroll
  for (int m2 = 0; m2 < 4; ++m2)
#pragma unroll
    for (int n = 0; n < 4; ++n) {
      const int mk = isGate ? m2 : (m2 + 4);   // rows this wave stores
      f32x4 other = *(const f32x4*)(pareg + ((m2 * 4 + n) * 64 + l) * 16);
#pragma unroll
      for (int j = 0; j < 4; ++j) {
        const float g_ = isGate ? acc[mk][n][j] : other[j];
        const float u_ = isGate ? other[j] : acc[mk][n][j];
        const float s = g_ / (1.0f + expf(-g_));
        const int row = m0 + wr * 128 + mk * 16 + er + j;
        const int col = n0 + (wc & 1) * 64 + n * 16 + ec;
        H[(size_t)row * N + col] = f32_to_bf16(s * u_);
      }
    }
}

// ---------------------------------------------------------------------------
// Output GEMM. BM=BN=256, BK=32, 8 waves (2M x 4N), per-wave 128x64.
// Same phase-locked schedule. H:[4096][11008] bf16 x W3 -> Out f32.
// ---------------------------------------------------------------------------
__global__ void __launch_bounds__(512, 2) k_gemm_out(
    const unsigned short* __restrict__ Hm,
    const unsigned short* __restrict__ W3,
    float* __restrict__ Out) {
  constexpr int K = 11008, N = 4096, NK = K / 32;
  __shared__ char ldsb[131072];

  const int tid = threadIdx.x;
  const int w = tid >> 6, l = tid & 63;

  const int bid = blockIdx.x;              // 256 = 8 * 32
  const int lt = (bid & 7) * 32 + (bid >> 3);
  const int mt = lt & 15, nt = lt >> 4;
  const int m0 = mt * 256, n0 = nt * 256;

  const int wr = w >> 2, wc = w & 3;

  const int lrow = l >> 2;
  const int kc8 = (((l & 3) ^ ((l >> 3) & 3)) << 3);
  const int arow = (w & 3) * 16 + (w >> 2) * 128;
  const unsigned short* sA[2] = {
      Hm + (size_t)(m0 + arow + lrow) * K + kc8,
      Hm + (size_t)(m0 + 64 + arow + lrow) * K + kc8};
  const unsigned short* sB[2] = {
      W3 + (size_t)(n0 + 16 * w + lrow) * K + kc8,
      W3 + (size_t)(n0 + 128 + 16 * w + lrow) * K + kc8};

#define STG(t, h) { const int bo_ = ((t) & 3) * 32768 + (h) * 8192 + w * 1024; \
    gload16(sA[h] + (size_t)(t) * 32, ldsb + bo_);                              \
    gload16(sB[h] + (size_t)(t) * 32, ldsb + bo_ + 16384); }

  const int roff = (((l >> 4) ^ ((l >> 1) & 3)) << 4);
  const char* rdA = ldsb + (wr * 64 + (l & 15)) * 64 + roff;
  const char* rdB = ldsb + 16384 + (wc * 64 + (l & 15)) * 64 + roff;

  f32x4 acc[8][4] = {};
  bf16x8 a[4], b[4];

  STG(0, 0); STG(0, 1); STG(1, 0); STG(1, 1);
  WAITV(4);
  barrier_nodrain();

  for (int t = 0; t < NK; ++t) {
    const int bo = (t & 3) * 32768;
#pragma unroll
    for (int m = 0; m < 4; ++m) a[m] = *(const bf16x8*)(rdA + bo + m * 1024);
#pragma unroll
    for (int n = 0; n < 4; ++n) b[n] = *(const bf16x8*)(rdB + bo + n * 1024);
    if (t + 2 < NK) STG(t + 2, 0);
    barrier_nodrain();
    __builtin_amdgcn_s_setprio(1);
#pragma unroll
    for (int m = 0; m < 4; ++m)
#pragma unroll
      for (int n = 0; n < 4; ++n)
        acc[m][n] = __builtin_amdgcn_mfma_f32_16x16x32_bf16(a[m], b[n], acc[m][n], 0, 0, 0);
    __builtin_amdgcn_s_setprio(0);
    barrier_nodrain();
#pragma unroll
    for (int m = 0; m < 4; ++m) a[m] = *(const bf16x8*)(rdA + bo + 8192 + m * 1024);
    if (t + 2 < NK) STG(t + 2, 1);
    barrier_nodrain();
    __builtin_amdgcn_s_setprio(1);
#pragma unroll
    for (int m = 0; m < 4; ++m)
#pragma unroll
      for (int n = 0; n < 4; ++n)
        acc[m + 4][n] = __builtin_amdgcn_mfma_f32_16x16x32_bf16(a[m], b[n], acc[m + 4][n], 0, 0, 0);
    __builtin_amdgcn_s_setprio(0);
    if (t + 2 < NK)      { WAITV(4); }
    else if (t + 1 < NK) { WAITV(0); }
    barrier_nodrain();
  }
#undef STG

  const int er = (l >> 4) * 4, ec = l & 15;
#pragma unroll
  for (int m = 0; m < 8; ++m)
#pragma unroll
    for (int n = 0; n < 4; ++n) {
      const int row = m0 + wr * 128 + m * 16 + er;
      const int col = n0 + wc * 64 + n * 16 + ec;
      float* ptr = Out + (size_t)row * N + col;
#pragma unroll
      for (int j = 0; j < 4; ++j) ptr[(size_t)j * N] = acc[m][n][j];
    }
}

// ---------------------------------------------------------------------------
extern "C" void kernel_launch(void* const* d_in, const int* in_sizes, int n_in,
                              void* d_out, int out_size, void* d_ws, size_t ws_size,
                              hipStream_t stream) {
  const float* x  = (const float*)d_in[0];   // [2,2048,4096] -> [4096][4096]
  const float* w1 = (const float*)d_in[1];   // [11008,4096]
  const float* w2 = (const float*)d_in[2];   // [11008,4096]
  const float* w3 = (const float*)d_in[3];   // [4096,11008]
  float* out = (float*)d_out;

  char* ws = (char*)d_ws;
  unsigned short* xb  = (unsigned short*)(ws);                // 32 MiB
  unsigned short* w1b = (unsigned short*)(ws + 33554432);     // 86 MiB
  unsigned short* w2b = (unsigned short*)(ws + 123731968);    // 86 MiB
  unsigned short* hb  = (unsigned short*)(ws + 213909504);    // 86 MiB
  unsigned short* w3b = w1b;  // reuse after gemm1 (stream-ordered)

  const int NW = 11008 * 4096 / 4;
  k_f32_to_bf16<<<16384, 256, 0, stream>>>(x, xb, 4096 * 4096 / 4);
  k_dequant_nf4<<<NW / 256, 256, 0, stream>>>(w1, w1b, NW);
  k_dequant_nf4<<<NW / 256, 256, 0, stream>>>(w2, w2b, NW);

  // gate/up + SwiGLU -> h  (M=4096, N=11008, K=4096)
  k_gemm_dual_swiglu<<<1376, 512, 0, stream>>>(xb, w1b, w2b, hb);

  k_dequant_nf4<<<NW / 256, 256, 0, stream>>>(w3, w3b, NW);

  // out = h . w3^T  (M=4096, N=4096, K=11008)
  k_gemm_out<<<256, 512, 0, stream>>>(hb, w3b, out);
}